// Round 14
// baseline (47.884 us; speedup 1.0000x reference)
//
#include <hip/hip_runtime.h>
#include <stdint.h>

// Floyd-Steinberg halftoning, TWO-KERNEL split (mono-directional streams).
//
// R2-R13: five structures (occupancy 10-60%, VALU 13-42%, forced MLP,
// counted-vmcnt pipeline, 1/2/4/8 lanes/tile) all plateau at 37.7-39.4us =
// ~85% of the D2D-copy ceiling. Common untested property: one bidirectional
// kernel whose 98MB write stream churns L3 (read FETCH stuck at 50%).
// Split: K1 reads 100MB input -> gray -> FS -> 32B/tile record (4MiB to
// d_ws). K2 reads records -> expands -> writes 96MiB output. Each kernel is
// a one-direction stream; during K1 the input fits L3 entirely (100+4MB),
// during K2 writes run at fill-like rates. Fallback: fused R10 kernel if
// ws_size < 4MiB.
//
// Record layout per tile (32B): u64 H (bit j*8+i: halftone on at row j,col i),
// u64 Z0,Z1,Z2 (bit r*8+c: channel input==0 at row r,col c).
// Exact reference math, contract(off): ((0.114*s0)+(0.587*s1))+(0.299*s2);
// FS on the transposed tile (reference swapaxes).

#define IMG_H 1024
#define IMG_W 1024
#define NCH   3

typedef float v4f __attribute__((ext_vector_type(4)));
typedef unsigned long long u64;

// spread 8 bits to every 8th bit of a u64 (bit j -> bit 8j)
__device__ __forceinline__ u64 spread8(unsigned int x) {
    u64 v = x;
    v = (v | (v << 28)) & 0x0000000F0000000Full;
    v = (v | (v << 14)) & 0x0003000300030003ull;
    v = (v | (v << 7))  & 0x0101010101010101ull;
    return v;
}

__device__ __forceinline__ u64 or_reduce8(u64 v) {
    unsigned int lo = (unsigned int)v, hi = (unsigned int)(v >> 32);
#pragma unroll
    for (int d = 1; d < 8; d <<= 1) {
        lo |= __shfl_xor(lo, d);
        hi |= __shfl_xor(hi, d);
    }
    return ((u64)hi << 32) | lo;
}

// ---------------- K1: read + gray + FS -> 32B/tile records ----------------
__global__ __launch_bounds__(256, 6)
void fs_stage1(const float* __restrict__ in, unsigned int* __restrict__ rec,
               int n_imgs) {
#pragma clang fp contract(off)
    const int tiles_w = IMG_W / 8;
    const int tiles_per_img = tiles_w * (IMG_H / 8);

    int gtid = blockIdx.x * blockDim.x + threadIdx.x;
    int tile = gtid >> 3;
    int col  = gtid & 7;
    int lane = threadIdx.x & 63;
    int b  = tile / tiles_per_img;
    if (b >= n_imgs) return;
    int t  = tile % tiles_per_img;
    int th = t / tiles_w;
    int tw = t % tiles_w;

    const size_t imgstride = (size_t)IMG_H * IMG_W;
    const float* base = in + (size_t)b * NCH * imgstride
                      + (size_t)(th * 8) * IMG_W + (size_t)(tw * 8) + (size_t)col;

    float a0[8], a1[8], a2[8];
#pragma unroll
    for (int r = 0; r < 8; ++r) a0[r] = base[0 * imgstride + (size_t)r * IMG_W];
#pragma unroll
    for (int r = 0; r < 8; ++r) a1[r] = base[1 * imgstride + (size_t)r * IMG_W];
#pragma unroll
    for (int r = 0; r < 8; ++r) a2[r] = base[2 * imgstride + (size_t)r * IMG_W];

    float p[8];
    unsigned int zm0 = 0u, zm1 = 0u, zm2 = 0u;     // bit r (own column)
#pragma unroll
    for (int r = 0; r < 8; ++r) {
        float s0 = a0[r] * 255.0f;
        float s1 = a1[r] * 255.0f;
        float s2 = a2[r] * 255.0f;
        if (s0 == 0.0f) zm0 |= 1u << r;
        if (s1 == 0.0f) zm1 |= 1u << r;
        if (s2 == 0.0f) zm2 |= 1u << r;
        p[r] = ((0.114f * s0) + (0.587f * s1)) + (0.299f * s2);
    }

    // FS transposed, redundant across the 8 lanes of the tile
    float nrow[8];
#pragma unroll
    for (int j = 0; j < 8; ++j) nrow[j] = 0.0f;
    unsigned int ob = 0u;                          // own column on-bits, bit j
#pragma unroll
    for (int i = 0; i < 8; ++i) {
        float cv[8];
#pragma unroll
        for (int j = 0; j < 8; ++j)
            cv[j] = __shfl(p[j], (lane & ~7) | i);
        float errs[8];
        float er = 0.0f;
        unsigned int onb = 0u;
#pragma unroll
        for (int j = 0; j < 8; ++j) {
            float px  = cv[j] + nrow[j];
            float old = px + er;
            bool  on  = old > 127.0f;
            float nw  = on ? 255.0f : 0.0f;
            float e   = old - nw;
            er = e * 0.4375f;                      // 7/16
            errs[j] = e;
            if (on) onb |= 1u << j;
        }
        if (col == i) ob = onb;
#pragma unroll
        for (int j = 0; j < 8; ++j) {
            float en = (j < 7) ? errs[j + 1] : 0.0f;
            float ep = (j > 0) ? errs[j - 1] : 0.0f;
            nrow[j] = ((0.3125f * errs[j]) + (0.1875f * en)) + (0.0625f * ep);
        }
    }

    // assemble per-tile u64s across the 8 lanes (OR-butterfly)
    u64 H  = or_reduce8(spread8(ob)  << col);
    u64 Z0 = or_reduce8(spread8(zm0) << col);
    u64 Z1 = or_reduce8(spread8(zm1) << col);
    u64 Z2 = or_reduce8(spread8(zm2) << col);

    // lane c stores u32 word c of the 32B record -> 256B contiguous per wave
    u64 sel = (col < 2) ? H : ((col < 4) ? Z0 : ((col < 6) ? Z1 : Z2));
    unsigned int w = (col & 1) ? (unsigned int)(sel >> 32) : (unsigned int)sel;
    rec[gtid] = w;
}

// ---------------- K2: records -> 96MiB output (pure write stream) ---------
__global__ __launch_bounds__(256)
void fs_stage2(const unsigned int* __restrict__ rec, float* __restrict__ out,
               int n_imgs) {
    const int tiles_w = IMG_W / 8;
    const int tiles_per_img = tiles_w * (IMG_H / 8);

    int gtid = blockIdx.x * blockDim.x + threadIdx.x;
    int tile = gtid >> 1;
    int hh   = gtid & 1;                           // cols 4*hh .. 4*hh+3
    int b  = tile / tiles_per_img;
    if (b >= n_imgs) return;
    int t  = tile % tiles_per_img;
    int th = t / tiles_w;
    int tw = t % tiles_w;

    const u64* rp = (const u64*)(rec) + (size_t)tile * 4;
    u64 H  = rp[0];
    u64 Z0 = rp[1];
    u64 Z1 = rp[2];
    u64 Z2 = rp[3];

    const size_t imgstride = (size_t)IMG_H * IMG_W;
    float* obase = out + (size_t)b * NCH * imgstride
                 + (size_t)(th * 8) * IMG_W + (size_t)(tw * 8) + (size_t)(hh * 4);

#pragma unroll
    for (int ch = 0; ch < 3; ++ch) {
        u64 Z = (ch == 0) ? Z0 : ((ch == 1) ? Z1 : Z2);
#pragma unroll
        for (int r = 0; r < 8; ++r) {
            v4f v;
#pragma unroll
            for (int k = 0; k < 4; ++k) {
                int bit = r * 8 + hh * 4 + k;
                bool on = (H >> bit) & 1ull;
                bool z  = (Z >> bit) & 1ull;
                v[k] = (on && !z) ? 1.0f : 0.0f;
            }
            *(v4f*)(obase + ch * imgstride + (size_t)r * IMG_W) = v;
        }
    }
}

// ---------------- fallback: fused R10 kernel (proven) ---------------------
__global__ __launch_bounds__(256, 6)
void fs_fused(const float* __restrict__ in, float* __restrict__ out,
              int n_imgs) {
#pragma clang fp contract(off)
    const int tiles_w = IMG_W / 8;
    const int tiles_per_img = tiles_w * (IMG_H / 8);

    int gtid = blockIdx.x * blockDim.x + threadIdx.x;
    int tile = gtid >> 3;
    int col  = gtid & 7;
    int lane = threadIdx.x & 63;
    int b  = tile / tiles_per_img;
    if (b >= n_imgs) return;
    int t  = tile % tiles_per_img;
    int th = t / tiles_w;
    int tw = t % tiles_w;

    const size_t imgstride = (size_t)IMG_H * IMG_W;
    const size_t col_off   = (size_t)(th * 8) * IMG_W + (size_t)(tw * 8) + (size_t)col;
    const float* base = in  + (size_t)b * NCH * imgstride + col_off;
    float*      obase = out + (size_t)b * NCH * imgstride + col_off;

    float a0[8], a1[8], a2[8];
#pragma unroll
    for (int r = 0; r < 8; ++r) a0[r] = base[0 * imgstride + (size_t)r * IMG_W];
#pragma unroll
    for (int r = 0; r < 8; ++r) a1[r] = base[1 * imgstride + (size_t)r * IMG_W];
#pragma unroll
    for (int r = 0; r < 8; ++r) a2[r] = base[2 * imgstride + (size_t)r * IMG_W];

    float p[8];
    unsigned int zm0 = 0u, zm1 = 0u, zm2 = 0u;
#pragma unroll
    for (int r = 0; r < 8; ++r) {
        float s0 = a0[r] * 255.0f;
        float s1 = a1[r] * 255.0f;
        float s2 = a2[r] * 255.0f;
        if (s0 == 0.0f) zm0 |= 1u << r;
        if (s1 == 0.0f) zm1 |= 1u << r;
        if (s2 == 0.0f) zm2 |= 1u << r;
        p[r] = ((0.114f * s0) + (0.587f * s1)) + (0.299f * s2);
    }

    float nrow[8];
#pragma unroll
    for (int j = 0; j < 8; ++j) nrow[j] = 0.0f;
    unsigned int ob = 0u;
#pragma unroll
    for (int i = 0; i < 8; ++i) {
        float cv[8];
#pragma unroll
        for (int j = 0; j < 8; ++j)
            cv[j] = __shfl(p[j], (lane & ~7) | i);
        float errs[8];
        float er = 0.0f;
        unsigned int onb = 0u;
#pragma unroll
        for (int j = 0; j < 8; ++j) {
            float px  = cv[j] + nrow[j];
            float old = px + er;
            bool  on  = old > 127.0f;
            float nw  = on ? 255.0f : 0.0f;
            float e   = old - nw;
            er = e * 0.4375f;
            errs[j] = e;
            if (on) onb |= 1u << j;
        }
        if (col == i) ob = onb;
#pragma unroll
        for (int j = 0; j < 8; ++j) {
            float en = (j < 7) ? errs[j + 1] : 0.0f;
            float ep = (j > 0) ? errs[j - 1] : 0.0f;
            nrow[j] = ((0.3125f * errs[j]) + (0.1875f * en)) + (0.0625f * ep);
        }
    }

#pragma unroll
    for (int ch = 0; ch < 3; ++ch) {
        unsigned int zm = (ch == 0) ? zm0 : ((ch == 1) ? zm1 : zm2);
#pragma unroll
        for (int r = 0; r < 8; ++r) {
            bool on = (ob >> r) & 1u;
            bool z  = (zm >> r) & 1u;
            obase[ch * imgstride + (size_t)r * IMG_W] = (on && !z) ? 1.0f : 0.0f;
        }
    }
}

extern "C" void kernel_launch(void* const* d_in, const int* in_sizes, int n_in,
                              void* d_out, int out_size, void* d_ws, size_t ws_size,
                              hipStream_t stream) {
    const float* in  = (const float*)d_in[0];
    float*       out = (float*)d_out;

    int n_imgs = in_sizes[0] / (NCH * IMG_H * IMG_W);  // 8
    int total_tiles = n_imgs * (IMG_H / 8) * (IMG_W / 8);
    size_t rec_bytes = (size_t)total_tiles * 32;

    if (ws_size >= rec_bytes) {
        unsigned int* rec = (unsigned int*)d_ws;
        int thr1 = 8 * total_tiles;
        fs_stage1<<<(thr1 + 255) / 256, 256, 0, stream>>>(in, rec, n_imgs);
        int thr2 = 2 * total_tiles;
        fs_stage2<<<(thr2 + 255) / 256, 256, 0, stream>>>(rec, out, n_imgs);
    } else {
        int thr = 8 * total_tiles;
        fs_fused<<<(thr + 255) / 256, 256, 0, stream>>>(in, out, n_imgs);
    }
}